// Round 6
// baseline (560.248 us; speedup 1.0000x reference)
//
#include <hip/hip_runtime.h>
#include <hip/hip_bf16.h>

#define DIN 96
#define DOUT 32
#define NH 4
#define DTOT 128          // NH * DOUT, concat output width
#define SLOPE 0.2f
#define NPB 16            // nodes per block in feat_kernel
#define BSH 7             // bucket shift: 128 src nodes per bucket
#define BNODES 128
#define MAXB 1024         // max buckets (N <= 131072)
#define EPB 8192          // edges per partition block
#define BMAX 512          // max partition blocks (E <= 4.19M)

// pack two fp32 -> two bf16 (RNE) in one uint
__device__ __forceinline__ unsigned int packbf2(float lo, float hi) {
    unsigned int a = __float_as_uint(lo), b = __float_as_uint(hi);
    a += 0x7fffu + ((a >> 16) & 1u);
    b += 0x7fffu + ((b >> 16) & 1u);
    return (a >> 16) | (b & 0xffff0000u);
}

// ---------------------------------------------------------------------------
// Kernel A: h[n] = x[n] @ W (all heads) stored as packed bf16, plus per-node
// attention exp factors (ee = exp(-leaky(as+ad)) = min(u.x*v.x, u.y*v.y)).
// ---------------------------------------------------------------------------
__global__ __launch_bounds__(256) void feat_kernel(
    const float* __restrict__ x, const float* __restrict__ W,
    const float* __restrict__ a,
    unsigned int* __restrict__ hq,      // [N*64] packed bf16 pairs
    float2* __restrict__ usrc, float2* __restrict__ vdst,
    int n_nodes)
{
    __shared__ float Wl[DIN * DTOT];
    __shared__ float xs[NPB * DIN];
    __shared__ float al[NH * 2 * DOUT];
    const int t = threadIdx.x;

    for (int i = t; i < DIN * DTOT; i += 256) {
        int k = i >> 7, c = i & 127;
        int head = c >> 5, j = c & 31;
        Wl[i] = W[head * (DIN * DOUT) + k * DOUT + j];
    }
    for (int i = t; i < NH * 2 * DOUT; i += 256) al[i] = a[i];

    const int node0 = blockIdx.x * NPB;
    for (int i = t; i < NPB * DIN; i += 256) {
        int gidx = node0 * DIN + i;
        xs[i] = (gidx < n_nodes * DIN) ? x[gidx] : 0.f;
    }
    __syncthreads();

    const int node = t >> 4;
    const int cb = (t & 15) << 3;
    float acc[8];
#pragma unroll
    for (int j = 0; j < 8; ++j) acc[j] = 0.f;

#pragma unroll 4
    for (int k = 0; k < DIN; ++k) {
        float xv = xs[node * DIN + k];
#pragma unroll
        for (int j = 0; j < 8; ++j)
            acc[j] += xv * Wl[k * DTOT + cb + j];
    }

    const int g = node0 + node;
    if (g < n_nodes) {
        uint4 pk;
        pk.x = packbf2(acc[0], acc[1]);
        pk.y = packbf2(acc[2], acc[3]);
        pk.z = packbf2(acc[4], acc[5]);
        pk.w = packbf2(acc[6], acc[7]);
        *(uint4*)&hq[(size_t)g * 64 + (cb >> 1)] = pk;
    }

    const int head = cb >> 5;
    const int j0 = cb & 31;
    float ps = 0.f, pd = 0.f;
#pragma unroll
    for (int j = 0; j < 8; ++j) {
        ps += acc[j] * al[head * 64 + j0 + j];
        pd += acc[j] * al[head * 64 + 32 + j0 + j];
    }
    ps += __shfl_xor(ps, 1); ps += __shfl_xor(ps, 2);
    pd += __shfl_xor(pd, 1); pd += __shfl_xor(pd, 2);
    if ((t & 3) == 0 && g < n_nodes) {
        usrc[g * NH + head] = make_float2(__expf(-ps), __expf(-SLOPE * ps));
        vdst[g * NH + head] = make_float2(__expf(-pd), __expf(-SLOPE * pd));
    }
}

// ---------------------------------------------------------------------------
// Block-private radix partition of edges by coarse bucket (src >> 7).
// No global atomics anywhere; every (block,bucket) run in `binned` is
// exclusively owned by one block.
// ---------------------------------------------------------------------------

// counts[b*nb + k]: private histogram row per block (writes all nb entries)
__global__ __launch_bounds__(256) void bincount_kernel(
    const int* __restrict__ esrc, int* __restrict__ counts,
    int n_edges, int nb)
{
    __shared__ int bc[MAXB];
    const int t = threadIdx.x;
    for (int i = t; i < nb; i += 256) bc[i] = 0;
    __syncthreads();
    const int base = blockIdx.x * EPB;
    const int end = min(base + EPB, n_edges);
    int i = base + (t << 2);
    for (; i + 3 < end; i += 1024) {
        int4 s4 = *(const int4*)(esrc + i);
        atomicAdd(&bc[s4.x >> BSH], 1);
        atomicAdd(&bc[s4.y >> BSH], 1);
        atomicAdd(&bc[s4.z >> BSH], 1);
        atomicAdd(&bc[s4.w >> BSH], 1);
    }
    for (; i < end; ++i) atomicAdd(&bc[esrc[i] >> BSH], 1);
    __syncthreads();
    for (int k = t; k < nb; k += 256)
        counts[blockIdx.x * nb + k] = bc[k];
}

// single block: bucket totals Tk, 4-aligned disjoint binned bases, slot bases
__global__ __launch_bounds__(1024) void scanB_kernel(
    const int* __restrict__ counts, int* __restrict__ Tk,
    int* __restrict__ bbase, int* __restrict__ sbase, int nb, int B)
{
    __shared__ int tmp[1024];
    const int t = threadIdx.x;
    int s = 0;
    if (t < nb) {
        for (int b = 0; b < B; ++b) s += counts[b * nb + t];
    }
    tmp[t] = s;
    __syncthreads();
    for (int off = 1; off < 1024; off <<= 1) {
        int xv = (t >= off) ? tmp[t - off] : 0;
        __syncthreads();
        tmp[t] += xv;
        __syncthreads();
    }
    if (t < nb) {
        int excl = tmp[t] - s;
        Tk[t] = s;
        bbase[t] = ((excl + 3) & ~3) + t * 4;            // 4-aligned, disjoint
        sbase[t] = ((excl + 3) & ~3) + t * (4 * BNODES); // slots base w/ pad slack
    }
}

// one block per bucket k: exclusive scan over partition blocks ->
// woff[k*B + b] = bbase[k] + sum_{b'<b} counts[b'][k]   (private writes)
__global__ __launch_bounds__(512) void scanC_kernel(
    const int* __restrict__ counts, const int* __restrict__ bbase,
    int* __restrict__ woff, int nb, int B)
{
    __shared__ int tmp[512];
    const int k = blockIdx.x;
    const int t = threadIdx.x;
    int v = (t < B) ? counts[t * nb + k] : 0;
    tmp[t] = v;
    __syncthreads();
    for (int off = 1; off < 512; off <<= 1) {
        int xv = (t >= off) ? tmp[t - off] : 0;
        __syncthreads();
        tmp[t] += xv;
        __syncthreads();
    }
    if (t < B) woff[k * B + t] = bbase[k] + tmp[t] - v;
}

// scatter edges into exclusively-owned (block,bucket) runs; LDS cursors only
__global__ __launch_bounds__(256) void binscatter_kernel(
    const int* __restrict__ esrc, const int* __restrict__ edst,
    const int* __restrict__ woff, unsigned int* __restrict__ binned,
    int n_edges, int nb, int B)
{
    __shared__ int cur[MAXB];
    const int t = threadIdx.x;
    const int b = blockIdx.x;
    for (int k = t; k < nb; k += 256) cur[k] = woff[k * B + b];
    __syncthreads();
    const int base = b * EPB;
    const int end = min(base + EPB, n_edges);
    int i = base + (t << 2);
    for (; i + 3 < end; i += 1024) {
        int4 s4 = *(const int4*)(esrc + i);
        int4 d4 = *(const int4*)(edst + i);
        int p0 = atomicAdd(&cur[s4.x >> BSH], 1);
        int p1 = atomicAdd(&cur[s4.y >> BSH], 1);
        int p2 = atomicAdd(&cur[s4.z >> BSH], 1);
        int p3 = atomicAdd(&cur[s4.w >> BSH], 1);
        binned[p0] = ((unsigned int)(s4.x & (BNODES - 1)) << 17) | (unsigned int)d4.x;
        binned[p1] = ((unsigned int)(s4.y & (BNODES - 1)) << 17) | (unsigned int)d4.y;
        binned[p2] = ((unsigned int)(s4.z & (BNODES - 1)) << 17) | (unsigned int)d4.z;
        binned[p3] = ((unsigned int)(s4.w & (BNODES - 1)) << 17) | (unsigned int)d4.w;
    }
    for (; i < end; ++i) {
        int s = esrc[i];
        int pos = atomicAdd(&cur[s >> BSH], 1);
        binned[pos] = ((unsigned int)(s & (BNODES - 1)) << 17) | (unsigned int)edst[i];
    }
}

// per-bucket fine sort: LDS per-node hist + scan, write offs/deg and slots
__global__ __launch_bounds__(256) void binfine_kernel(
    const unsigned int* __restrict__ binned,
    const int* __restrict__ Tk, const int* __restrict__ bbase,
    const int* __restrict__ sbase,
    int* __restrict__ offs, int* __restrict__ deg,
    int* __restrict__ slots, int n_nodes)
{
    __shared__ int dcnt[BNODES];
    __shared__ int sc[BNODES];
    __shared__ int dcur[BNODES];
    const int t = threadIdx.x;
    const int b = blockIdx.x;
    const int cnt = Tk[b];
    const int start = bbase[b];     // 4-aligned
    const int sb = sbase[b];
    const int node0 = b << BSH;

    if (t < BNODES) dcnt[t] = 0;
    __syncthreads();
    int i = t << 2;
    for (; i + 3 < cnt; i += 1024) {
        uint4 w4 = *(const uint4*)(binned + start + i);
        atomicAdd(&dcnt[w4.x >> 17], 1);
        atomicAdd(&dcnt[w4.y >> 17], 1);
        atomicAdd(&dcnt[w4.z >> 17], 1);
        atomicAdd(&dcnt[w4.w >> 17], 1);
    }
    for (; i < cnt; ++i) atomicAdd(&dcnt[binned[start + i] >> 17], 1);
    __syncthreads();
    int pd = 0;
    if (t < BNODES) { pd = (dcnt[t] + 3) & ~3; sc[t] = pd; }
    __syncthreads();
    for (int off = 1; off < BNODES; off <<= 1) {
        int v = 0;
        if (t < BNODES && t >= off) v = sc[t - off];
        __syncthreads();
        if (t < BNODES) sc[t] += v;
        __syncthreads();
    }
    if (t < BNODES) {
        int o = sb + sc[t] - pd;   // 4-aligned per-node start
        dcur[t] = o;
        int node = node0 + t;
        if (node < n_nodes) { offs[node] = o; deg[node] = dcnt[t]; }
    }
    __syncthreads();
    i = t << 2;
    for (; i + 3 < cnt; i += 1024) {
        uint4 w4 = *(const uint4*)(binned + start + i);
        int p0 = atomicAdd(&dcur[w4.x >> 17], 1);
        int p1 = atomicAdd(&dcur[w4.y >> 17], 1);
        int p2 = atomicAdd(&dcur[w4.z >> 17], 1);
        int p3 = atomicAdd(&dcur[w4.w >> 17], 1);
        slots[p0] = (int)(w4.x & 0x1ffffu);
        slots[p1] = (int)(w4.y & 0x1ffffu);
        slots[p2] = (int)(w4.z & 0x1ffffu);
        slots[p3] = (int)(w4.w & 0x1ffffu);
    }
    for (; i < cnt; ++i) {
        unsigned int w = binned[start + i];
        int pos = atomicAdd(&dcur[w >> 17], 1);
        slots[pos] = (int)(w & 0x1ffffu);
    }
}

// ---------------------------------------------------------------------------
// Gather: 64 lanes per node, 2 cols per lane (bf16x2 h loads). Edge loop
// unrolled x4 with pipelined int4 slot prefetch, fused ELU, no atomics.
// ---------------------------------------------------------------------------
__global__ __launch_bounds__(256) void gather_kernel(
    const int* __restrict__ slots, const int* __restrict__ offsets,
    const int* __restrict__ deg,
    const unsigned int* __restrict__ hv,    // [N*64] packed bf16 pairs
    const float2* __restrict__ usrc, const float2* __restrict__ vdst,
    float* __restrict__ out, int n_nodes)
{
    const int t = threadIdx.x;
    const int node = blockIdx.x * 4 + (t >> 6);
    if (node >= n_nodes) return;
    const int l = t & 63;          // cols {2l, 2l+1}
    const int head = l >> 4;
    const float2 u = usrc[node * NH + head];
    const int beg = offsets[node]; // multiple of 4
    const int d = deg[node];

    float ax0 = 0.f, ay0 = 0.f, ax1 = 0.f, ay1 = 0.f;
    float ax2 = 0.f, ay2 = 0.f, ax3 = 0.f, ay3 = 0.f;
    int k = 0;
    int4 dd = (d >= 4) ? *(const int4*)(slots + beg) : make_int4(0, 0, 0, 0);
    for (; k + 4 <= d; k += 4) {
        const int4 cur = dd;
        if (k + 8 <= d) dd = *(const int4*)(slots + beg + k + 4);
        float2 v0 = vdst[cur.x * NH + head];
        float2 v1 = vdst[cur.y * NH + head];
        float2 v2 = vdst[cur.z * NH + head];
        float2 v3 = vdst[cur.w * NH + head];
        unsigned int w0 = hv[(size_t)cur.x * 64 + l];
        unsigned int w1 = hv[(size_t)cur.y * 64 + l];
        unsigned int w2 = hv[(size_t)cur.z * 64 + l];
        unsigned int w3 = hv[(size_t)cur.w * 64 + l];
        float e0 = fminf(u.x * v0.x, u.y * v0.y);
        float e1 = fminf(u.x * v1.x, u.y * v1.y);
        float e2 = fminf(u.x * v2.x, u.y * v2.y);
        float e3 = fminf(u.x * v3.x, u.y * v3.y);
        ax0 = fmaf(e0, __uint_as_float(w0 << 16), ax0);
        ay0 = fmaf(e0, __uint_as_float(w0 & 0xffff0000u), ay0);
        ax1 = fmaf(e1, __uint_as_float(w1 << 16), ax1);
        ay1 = fmaf(e1, __uint_as_float(w1 & 0xffff0000u), ay1);
        ax2 = fmaf(e2, __uint_as_float(w2 << 16), ax2);
        ay2 = fmaf(e2, __uint_as_float(w2 & 0xffff0000u), ay2);
        ax3 = fmaf(e3, __uint_as_float(w3 << 16), ax3);
        ay3 = fmaf(e3, __uint_as_float(w3 & 0xffff0000u), ay3);
    }
    for (; k < d; ++k) {
        int dst = slots[beg + k];
        float2 v = vdst[dst * NH + head];
        unsigned int w = hv[(size_t)dst * 64 + l];
        float e = fminf(u.x * v.x, u.y * v.y);
        ax0 = fmaf(e, __uint_as_float(w << 16), ax0);
        ay0 = fmaf(e, __uint_as_float(w & 0xffff0000u), ay0);
    }
    float rx = (ax0 + ax1) + (ax2 + ax3);
    float ry = (ay0 + ay1) + (ay2 + ay3);
    rx = rx > 0.f ? rx : __expf(rx) - 1.f;
    ry = ry > 0.f ? ry : __expf(ry) - 1.f;
    ((float2*)out)[(size_t)node * 64 + l] = make_float2(rx, ry);
}

extern "C" void kernel_launch(void* const* d_in, const int* in_sizes, int n_in,
                              void* d_out, int out_size, void* d_ws, size_t ws_size,
                              hipStream_t stream)
{
    const float* x  = (const float*)d_in[0];
    const float* W  = (const float*)d_in[1];
    const float* a  = (const float*)d_in[2];
    const int* esrc = (const int*)d_in[3];
    const int* edst = (const int*)d_in[4];
    const int n_nodes = in_sizes[0] / DIN;
    const int n_edges = in_sizes[3];
    float* out = (float*)d_out;

    const int nb = (n_nodes + BNODES - 1) >> BSH;
    const int B  = (n_edges + EPB - 1) / EPB;     // partition blocks (<= BMAX)
    const int nbB = ((nb * B + 3) & ~3);

    // workspace layout
    unsigned int* hq = (unsigned int*)d_ws;                 // [N*64] bf16 pairs
    float2* usrc = (float2*)(hq + (size_t)n_nodes * 64);    // [N*4]
    float2* vdst = usrc + (size_t)n_nodes * NH;             // [N*4]
    int* offs   = (int*)(vdst + (size_t)n_nodes * NH);      // [N]
    int* deg    = offs + n_nodes;                           // [N]
    int* Tk     = deg + n_nodes;                            // [MAXB]
    int* bbase  = Tk + MAXB;                                // [MAXB]
    int* sbase  = bbase + MAXB;                             // [MAXB]
    int* counts = sbase + MAXB;                             // [nb*B]
    int* woff   = counts + nbB;                             // [nb*B]
    unsigned int* binned = (unsigned int*)(woff + nbB);     // [E + 4*nb + 64]
    int* slots  = (int*)(binned + n_edges + 4 * nb + 64);   // [E + 512*nb + 64]

    feat_kernel<<<(n_nodes + NPB - 1) / NPB, 256, 0, stream>>>(
        x, W, a, hq, usrc, vdst, n_nodes);

    bincount_kernel<<<B, 256, 0, stream>>>(esrc, counts, n_edges, nb);
    scanB_kernel<<<1, 1024, 0, stream>>>(counts, Tk, bbase, sbase, nb, B);
    scanC_kernel<<<nb, 512, 0, stream>>>(counts, bbase, woff, nb, B);
    binscatter_kernel<<<B, 256, 0, stream>>>(
        esrc, edst, woff, binned, n_edges, nb, B);
    binfine_kernel<<<nb, 256, 0, stream>>>(
        binned, Tk, bbase, sbase, offs, deg, slots, n_nodes);

    gather_kernel<<<(n_nodes + 3) / 4, 256, 0, stream>>>(
        slots, offs, deg, hq, usrc, vdst, out, n_nodes);
}

// Round 7
// 550.017 us; speedup vs baseline: 1.0186x; 1.0186x over previous
//
#include <hip/hip_runtime.h>
#include <hip/hip_bf16.h>

#define DIN 96
#define DOUT 32
#define NH 4
#define DTOT 128          // NH * DOUT, concat output width
#define SLOPE 0.2f
#define NPB 16            // nodes per block in feat_kernel
#define BSH 7             // bucket shift: 128 src nodes per bucket
#define BNODES 128
#define MAXB 1024         // max buckets (N <= 131072)
#define EPB 8192          // edges per partition block
#define FCAP 6144         // binfine LDS value capacity (bucket cnt ~4096 +- 5 sigma)

// pack two fp32 -> two bf16 (RNE) in one uint
__device__ __forceinline__ unsigned int packbf2(float lo, float hi) {
    unsigned int a = __float_as_uint(lo), b = __float_as_uint(hi);
    a += 0x7fffu + ((a >> 16) & 1u);
    b += 0x7fffu + ((b >> 16) & 1u);
    return (a >> 16) | (b & 0xffff0000u);
}

// ---------------------------------------------------------------------------
// Kernel A: h[n] = x[n] @ W (all heads) stored as packed bf16, plus per-node
// attention exp factors (ee = exp(-leaky(as+ad)) = min(u.x*v.x, u.y*v.y)).
// ---------------------------------------------------------------------------
__global__ __launch_bounds__(256) void feat_kernel(
    const float* __restrict__ x, const float* __restrict__ W,
    const float* __restrict__ a,
    unsigned int* __restrict__ hq,      // [N*64] packed bf16 pairs
    float2* __restrict__ usrc, float2* __restrict__ vdst,
    int n_nodes)
{
    __shared__ float Wl[DIN * DTOT];
    __shared__ float xs[NPB * DIN];
    __shared__ float al[NH * 2 * DOUT];
    const int t = threadIdx.x;

    for (int i = t; i < DIN * DTOT; i += 256) {
        int k = i >> 7, c = i & 127;
        int head = c >> 5, j = c & 31;
        Wl[i] = W[head * (DIN * DOUT) + k * DOUT + j];
    }
    for (int i = t; i < NH * 2 * DOUT; i += 256) al[i] = a[i];

    const int node0 = blockIdx.x * NPB;
    for (int i = t; i < NPB * DIN; i += 256) {
        int gidx = node0 * DIN + i;
        xs[i] = (gidx < n_nodes * DIN) ? x[gidx] : 0.f;
    }
    __syncthreads();

    const int node = t >> 4;
    const int cb = (t & 15) << 3;
    float acc[8];
#pragma unroll
    for (int j = 0; j < 8; ++j) acc[j] = 0.f;

#pragma unroll 4
    for (int k = 0; k < DIN; ++k) {
        float xv = xs[node * DIN + k];
#pragma unroll
        for (int j = 0; j < 8; ++j)
            acc[j] += xv * Wl[k * DTOT + cb + j];
    }

    const int g = node0 + node;
    if (g < n_nodes) {
        uint4 pk;
        pk.x = packbf2(acc[0], acc[1]);
        pk.y = packbf2(acc[2], acc[3]);
        pk.z = packbf2(acc[4], acc[5]);
        pk.w = packbf2(acc[6], acc[7]);
        *(uint4*)&hq[(size_t)g * 64 + (cb >> 1)] = pk;
    }

    const int head = cb >> 5;
    const int j0 = cb & 31;
    float ps = 0.f, pd = 0.f;
#pragma unroll
    for (int j = 0; j < 8; ++j) {
        ps += acc[j] * al[head * 64 + j0 + j];
        pd += acc[j] * al[head * 64 + 32 + j0 + j];
    }
    ps += __shfl_xor(ps, 1); ps += __shfl_xor(ps, 2);
    pd += __shfl_xor(pd, 1); pd += __shfl_xor(pd, 2);
    if ((t & 3) == 0 && g < n_nodes) {
        usrc[g * NH + head] = make_float2(__expf(-ps), __expf(-SLOPE * ps));
        vdst[g * NH + head] = make_float2(__expf(-pd), __expf(-SLOPE * pd));
    }
}

// ---------------------------------------------------------------------------
// Block-private radix partition of edges by coarse bucket (src >> 7),
// with LDS staging so ALL global writes are wave-coalesced run copies.
// ---------------------------------------------------------------------------

// counts[b*nb + k]: private histogram row per block
__global__ __launch_bounds__(256) void bincount_kernel(
    const int* __restrict__ esrc, int* __restrict__ counts,
    int n_edges, int nb)
{
    __shared__ int bc[MAXB];
    const int t = threadIdx.x;
    for (int i = t; i < nb; i += 256) bc[i] = 0;
    __syncthreads();
    const int base = blockIdx.x * EPB;
    const int end = min(base + EPB, n_edges);
    int i = base + (t << 2);
    for (; i + 3 < end; i += 1024) {
        int4 s4 = *(const int4*)(esrc + i);
        atomicAdd(&bc[s4.x >> BSH], 1);
        atomicAdd(&bc[s4.y >> BSH], 1);
        atomicAdd(&bc[s4.z >> BSH], 1);
        atomicAdd(&bc[s4.w >> BSH], 1);
    }
    for (; i < end; ++i) atomicAdd(&bc[esrc[i] >> BSH], 1);
    __syncthreads();
    for (int k = t; k < nb; k += 256)
        counts[blockIdx.x * nb + k] = bc[k];
}

// single block: bucket totals Tk, 4-aligned disjoint binned bases, slot bases
__global__ __launch_bounds__(1024) void scanB_kernel(
    const int* __restrict__ counts, int* __restrict__ Tk,
    int* __restrict__ bbase, int* __restrict__ sbase, int nb, int B)
{
    __shared__ int tmp[1024];
    const int t = threadIdx.x;
    int s = 0;
    if (t < nb) {
        for (int b = 0; b < B; ++b) s += counts[b * nb + t];
    }
    tmp[t] = s;
    __syncthreads();
    for (int off = 1; off < 1024; off <<= 1) {
        int xv = (t >= off) ? tmp[t - off] : 0;
        __syncthreads();
        tmp[t] += xv;
        __syncthreads();
    }
    if (t < nb) {
        int excl = tmp[t] - s;
        Tk[t] = s;
        bbase[t] = ((excl + 3) & ~3) + t * 4;            // 4-aligned, disjoint
        sbase[t] = ((excl + 3) & ~3) + t * (4 * BNODES); // slots base w/ pad slack
    }
}

// one block per bucket k: exclusive scan over partition blocks ->
// woff[b*nb + k] = bbase[k] + sum_{b'<b} counts[b'][k]
__global__ __launch_bounds__(512) void scanC_kernel(
    const int* __restrict__ counts, const int* __restrict__ bbase,
    int* __restrict__ woff, int nb, int B)
{
    __shared__ int tmp[512];
    const int k = blockIdx.x;
    const int t = threadIdx.x;
    int v = (t < B) ? counts[t * nb + k] : 0;
    tmp[t] = v;
    __syncthreads();
    for (int off = 1; off < 512; off <<= 1) {
        int xv = (t >= off) ? tmp[t - off] : 0;
        __syncthreads();
        tmp[t] += xv;
        __syncthreads();
    }
    if (t < B) woff[t * nb + k] = bbase[k] + tmp[t] - v;
}

// LDS counting-sort of this block's edges, then wave-coalesced run copies.
__global__ __launch_bounds__(256) void binscatter_kernel(
    const int* __restrict__ esrc, const int* __restrict__ edst,
    const int* __restrict__ woff, unsigned int* __restrict__ binned,
    int n_edges, int nb, int B)
{
    __shared__ unsigned int vals[EPB];   // 32 KB
    __shared__ int lcnt[MAXB];
    __shared__ int lbase[MAXB];
    __shared__ int lcur[MAXB];
    __shared__ int wbase[MAXB];
    __shared__ int tsum[256];
    const int t = threadIdx.x;
    const int b = blockIdx.x;

    for (int k = t; k < nb; k += 256) {
        lcnt[k] = 0;
        wbase[k] = woff[b * nb + k];     // coalesced row load
    }
    __syncthreads();

    const int base = b * EPB;
    const int end = min(base + EPB, n_edges);
    int i = base + (t << 2);
    for (; i + 3 < end; i += 1024) {
        int4 s4 = *(const int4*)(esrc + i);
        atomicAdd(&lcnt[s4.x >> BSH], 1);
        atomicAdd(&lcnt[s4.y >> BSH], 1);
        atomicAdd(&lcnt[s4.z >> BSH], 1);
        atomicAdd(&lcnt[s4.w >> BSH], 1);
    }
    for (; i < end; ++i) atomicAdd(&lcnt[esrc[i] >> BSH], 1);
    __syncthreads();

    // scan lcnt -> lbase (256 threads x 4 buckets)
    const int k0 = t << 2;
    int l0 = (k0 + 0 < nb) ? lcnt[k0 + 0] : 0;
    int l1 = (k0 + 1 < nb) ? lcnt[k0 + 1] : 0;
    int l2 = (k0 + 2 < nb) ? lcnt[k0 + 2] : 0;
    int l3 = (k0 + 3 < nb) ? lcnt[k0 + 3] : 0;
    int s = l0 + l1 + l2 + l3;
    tsum[t] = s;
    __syncthreads();
    for (int off = 1; off < 256; off <<= 1) {
        int xv = (t >= off) ? tsum[t - off] : 0;
        __syncthreads();
        tsum[t] += xv;
        __syncthreads();
    }
    int run = tsum[t] - s;
    if (k0 + 0 < nb) { lbase[k0 + 0] = run; lcur[k0 + 0] = run; } run += l0;
    if (k0 + 1 < nb) { lbase[k0 + 1] = run; lcur[k0 + 1] = run; } run += l1;
    if (k0 + 2 < nb) { lbase[k0 + 2] = run; lcur[k0 + 2] = run; } run += l2;
    if (k0 + 3 < nb) { lbase[k0 + 3] = run; lcur[k0 + 3] = run; }
    __syncthreads();

    // LDS scatter (sorted by bucket)
    i = base + (t << 2);
    for (; i + 3 < end; i += 1024) {
        int4 s4 = *(const int4*)(esrc + i);
        int4 d4 = *(const int4*)(edst + i);
        int p0 = atomicAdd(&lcur[s4.x >> BSH], 1);
        int p1 = atomicAdd(&lcur[s4.y >> BSH], 1);
        int p2 = atomicAdd(&lcur[s4.z >> BSH], 1);
        int p3 = atomicAdd(&lcur[s4.w >> BSH], 1);
        vals[p0] = ((unsigned int)(s4.x & (BNODES - 1)) << 17) | (unsigned int)d4.x;
        vals[p1] = ((unsigned int)(s4.y & (BNODES - 1)) << 17) | (unsigned int)d4.y;
        vals[p2] = ((unsigned int)(s4.z & (BNODES - 1)) << 17) | (unsigned int)d4.z;
        vals[p3] = ((unsigned int)(s4.w & (BNODES - 1)) << 17) | (unsigned int)d4.w;
    }
    for (; i < end; ++i) {
        int sv = esrc[i];
        int pos = atomicAdd(&lcur[sv >> BSH], 1);
        vals[pos] = ((unsigned int)(sv & (BNODES - 1)) << 17) | (unsigned int)edst[i];
    }
    __syncthreads();

    // wave-coalesced run copies to global
    const int wv = t >> 6;
    const int lane = t & 63;
    for (int k = wv; k < nb; k += 4) {
        int len = lcnt[k];
        if (len == 0) continue;
        int lb = lbase[k];
        int gb = wbase[k];
        for (int j = lane; j < len; j += 64)
            binned[gb + j] = vals[lb + j];
    }
}

// per-bucket fine sort in LDS + wave-coalesced per-node run copies
__global__ __launch_bounds__(256) void binfine_kernel(
    const unsigned int* __restrict__ binned,
    const int* __restrict__ Tk, const int* __restrict__ bbase,
    const int* __restrict__ sbase,
    int* __restrict__ offs, int* __restrict__ deg,
    int* __restrict__ slots, int n_nodes)
{
    __shared__ unsigned int vals[FCAP];  // 24 KB
    __shared__ int dcnt[BNODES];
    __shared__ int gbase[BNODES];        // global slot start per node
    __shared__ int lbase[BNODES];        // LDS sorted start per node
    __shared__ int lcur[BNODES];
    const int t = threadIdx.x;
    const int b = blockIdx.x;
    const int cnt = Tk[b];
    const int start = bbase[b];     // 4-aligned
    const int sb = sbase[b];
    const int node0 = b << BSH;

    if (t < BNODES) dcnt[t] = 0;
    __syncthreads();
    int i = t << 2;
    for (; i + 3 < cnt; i += 1024) {
        uint4 w4 = *(const uint4*)(binned + start + i);
        atomicAdd(&dcnt[w4.x >> 17], 1);
        atomicAdd(&dcnt[w4.y >> 17], 1);
        atomicAdd(&dcnt[w4.z >> 17], 1);
        atomicAdd(&dcnt[w4.w >> 17], 1);
    }
    for (; i < cnt; ++i) atomicAdd(&dcnt[binned[start + i] >> 17], 1);
    __syncthreads();

    // scan 1: padded -> global offsets; scan 2: unpadded -> LDS offsets
    int pd = 0, ud = 0;
    if (t < BNODES) { pd = (dcnt[t] + 3) & ~3; ud = dcnt[t]; gbase[t] = pd; lbase[t] = ud; }
    __syncthreads();
    for (int off = 1; off < BNODES; off <<= 1) {
        int v1 = 0, v2 = 0;
        if (t < BNODES && t >= off) { v1 = gbase[t - off]; v2 = lbase[t - off]; }
        __syncthreads();
        if (t < BNODES) { gbase[t] += v1; lbase[t] += v2; }
        __syncthreads();
    }
    if (t < BNODES) {
        int go = sb + gbase[t] - pd;
        int lo = lbase[t] - ud;
        gbase[t] = go;
        lbase[t] = lo;
        lcur[t] = lo;
        int node = node0 + t;
        if (node < n_nodes) { offs[node] = go; deg[node] = dcnt[t]; }
    }
    __syncthreads();

    if (cnt <= FCAP) {
        // LDS scatter (sorted by node), store dst only
        i = t << 2;
        for (; i + 3 < cnt; i += 1024) {
            uint4 w4 = *(const uint4*)(binned + start + i);
            int p0 = atomicAdd(&lcur[w4.x >> 17], 1);
            int p1 = atomicAdd(&lcur[w4.y >> 17], 1);
            int p2 = atomicAdd(&lcur[w4.z >> 17], 1);
            int p3 = atomicAdd(&lcur[w4.w >> 17], 1);
            vals[p0] = w4.x & 0x1ffffu;
            vals[p1] = w4.y & 0x1ffffu;
            vals[p2] = w4.z & 0x1ffffu;
            vals[p3] = w4.w & 0x1ffffu;
        }
        for (; i < cnt; ++i) {
            unsigned int w = binned[start + i];
            int pos = atomicAdd(&lcur[w >> 17], 1);
            vals[pos] = w & 0x1ffffu;
        }
        __syncthreads();
        // wave-coalesced per-node run copies
        const int wv = t >> 6;
        const int lane = t & 63;
        for (int nd = wv; nd < BNODES; nd += 4) {
            int len = dcnt[nd];
            if (len == 0) continue;
            int lb = lbase[nd];
            int gb = gbase[nd];
            for (int j = lane; j < len; j += 64)
                slots[gb + j] = (int)vals[lb + j];
        }
    } else {
        // fallback (statistically never for this graph): direct scatter
        // reuse lcur (currently = lbase end state) -> reinit to global starts
        __syncthreads();
        if (t < BNODES) lcur[t] = gbase[t];
        __syncthreads();
        for (i = t; i < cnt; i += 256) {
            unsigned int w = binned[start + i];
            int pos = atomicAdd(&lcur[w >> 17], 1);
            slots[pos] = (int)(w & 0x1ffffu);
        }
    }
}

// ---------------------------------------------------------------------------
// Gather: 64 lanes per node, 2 cols per lane (bf16x2 h loads). Edge loop
// unrolled x4 with pipelined int4 slot prefetch, fused ELU, no atomics.
// ---------------------------------------------------------------------------
__global__ __launch_bounds__(256) void gather_kernel(
    const int* __restrict__ slots, const int* __restrict__ offsets,
    const int* __restrict__ deg,
    const unsigned int* __restrict__ hv,    // [N*64] packed bf16 pairs
    const float2* __restrict__ usrc, const float2* __restrict__ vdst,
    float* __restrict__ out, int n_nodes)
{
    const int t = threadIdx.x;
    const int node = blockIdx.x * 4 + (t >> 6);
    if (node >= n_nodes) return;
    const int l = t & 63;          // cols {2l, 2l+1}
    const int head = l >> 4;
    const float2 u = usrc[node * NH + head];
    const int beg = offsets[node]; // multiple of 4
    const int d = deg[node];

    float ax0 = 0.f, ay0 = 0.f, ax1 = 0.f, ay1 = 0.f;
    float ax2 = 0.f, ay2 = 0.f, ax3 = 0.f, ay3 = 0.f;
    int k = 0;
    int4 dd = (d >= 4) ? *(const int4*)(slots + beg) : make_int4(0, 0, 0, 0);
    for (; k + 4 <= d; k += 4) {
        const int4 cur = dd;
        if (k + 8 <= d) dd = *(const int4*)(slots + beg + k + 4);
        float2 v0 = vdst[cur.x * NH + head];
        float2 v1 = vdst[cur.y * NH + head];
        float2 v2 = vdst[cur.z * NH + head];
        float2 v3 = vdst[cur.w * NH + head];
        unsigned int w0 = hv[(size_t)cur.x * 64 + l];
        unsigned int w1 = hv[(size_t)cur.y * 64 + l];
        unsigned int w2 = hv[(size_t)cur.z * 64 + l];
        unsigned int w3 = hv[(size_t)cur.w * 64 + l];
        float e0 = fminf(u.x * v0.x, u.y * v0.y);
        float e1 = fminf(u.x * v1.x, u.y * v1.y);
        float e2 = fminf(u.x * v2.x, u.y * v2.y);
        float e3 = fminf(u.x * v3.x, u.y * v3.y);
        ax0 = fmaf(e0, __uint_as_float(w0 << 16), ax0);
        ay0 = fmaf(e0, __uint_as_float(w0 & 0xffff0000u), ay0);
        ax1 = fmaf(e1, __uint_as_float(w1 << 16), ax1);
        ay1 = fmaf(e1, __uint_as_float(w1 & 0xffff0000u), ay1);
        ax2 = fmaf(e2, __uint_as_float(w2 << 16), ax2);
        ay2 = fmaf(e2, __uint_as_float(w2 & 0xffff0000u), ay2);
        ax3 = fmaf(e3, __uint_as_float(w3 << 16), ax3);
        ay3 = fmaf(e3, __uint_as_float(w3 & 0xffff0000u), ay3);
    }
    for (; k < d; ++k) {
        int dst = slots[beg + k];
        float2 v = vdst[dst * NH + head];
        unsigned int w = hv[(size_t)dst * 64 + l];
        float e = fminf(u.x * v.x, u.y * v.y);
        ax0 = fmaf(e, __uint_as_float(w << 16), ax0);
        ay0 = fmaf(e, __uint_as_float(w & 0xffff0000u), ay0);
    }
    float rx = (ax0 + ax1) + (ax2 + ax3);
    float ry = (ay0 + ay1) + (ay2 + ay3);
    rx = rx > 0.f ? rx : __expf(rx) - 1.f;
    ry = ry > 0.f ? ry : __expf(ry) - 1.f;
    ((float2*)out)[(size_t)node * 64 + l] = make_float2(rx, ry);
}

extern "C" void kernel_launch(void* const* d_in, const int* in_sizes, int n_in,
                              void* d_out, int out_size, void* d_ws, size_t ws_size,
                              hipStream_t stream)
{
    const float* x  = (const float*)d_in[0];
    const float* W  = (const float*)d_in[1];
    const float* a  = (const float*)d_in[2];
    const int* esrc = (const int*)d_in[3];
    const int* edst = (const int*)d_in[4];
    const int n_nodes = in_sizes[0] / DIN;
    const int n_edges = in_sizes[3];
    float* out = (float*)d_out;

    const int nb = (n_nodes + BNODES - 1) >> BSH;
    const int B  = (n_edges + EPB - 1) / EPB;     // partition blocks
    const int nbB = ((nb * B + 3) & ~3);

    // workspace layout
    unsigned int* hq = (unsigned int*)d_ws;                 // [N*64] bf16 pairs
    float2* usrc = (float2*)(hq + (size_t)n_nodes * 64);    // [N*4]
    float2* vdst = usrc + (size_t)n_nodes * NH;             // [N*4]
    int* offs   = (int*)(vdst + (size_t)n_nodes * NH);      // [N]
    int* deg    = offs + n_nodes;                           // [N]
    int* Tk     = deg + n_nodes;                            // [MAXB]
    int* bbase  = Tk + MAXB;                                // [MAXB]
    int* sbase  = bbase + MAXB;                             // [MAXB]
    int* counts = sbase + MAXB;                             // [nb*B]
    int* woff   = counts + nbB;                             // [nb*B]
    unsigned int* binned = (unsigned int*)(woff + nbB);     // [E + 4*nb + 64]
    int* slots  = (int*)(binned + n_edges + 4 * nb + 64);   // [E + 512*nb + 64]

    feat_kernel<<<(n_nodes + NPB - 1) / NPB, 256, 0, stream>>>(
        x, W, a, hq, usrc, vdst, n_nodes);

    bincount_kernel<<<B, 256, 0, stream>>>(esrc, counts, n_edges, nb);
    scanB_kernel<<<1, 1024, 0, stream>>>(counts, Tk, bbase, sbase, nb, B);
    scanC_kernel<<<nb, 512, 0, stream>>>(counts, bbase, woff, nb, B);
    binscatter_kernel<<<B, 256, 0, stream>>>(
        esrc, edst, woff, binned, n_edges, nb, B);
    binfine_kernel<<<nb, 256, 0, stream>>>(
        binned, Tk, bbase, sbase, offs, deg, slots, n_nodes);

    gather_kernel<<<(n_nodes + 3) / 4, 256, 0, stream>>>(
        slots, offs, deg, hq, usrc, vdst, out, n_nodes);
}